// Round 1
// baseline (207.034 us; speedup 1.0000x reference)
//
#include <hip/hip_runtime.h>
#include <hip/hip_bf16.h>
#include <stdint.h>

typedef __bf16 bf16_t;
typedef __bf16 bf16x4 __attribute__((ext_vector_type(4)));
typedef __bf16 bf16x8 __attribute__((ext_vector_type(8)));
typedef float  f32x4  __attribute__((ext_vector_type(4)));

#define AS_GLOBAL __attribute__((address_space(1)))
#define AS_LDS    __attribute__((address_space(3)))

__device__ __forceinline__ void gload_lds16(const void* g, void* l) {
  __builtin_amdgcn_global_load_lds((const AS_GLOBAL void*)g,
                                   (AS_LDS void*)l, 16, 0, 0);
}

// ---------------- K0a: f32 -> bf16 elementwise (8 elems/thread) ----------------
__global__ void cvt_f32_bf16_kernel(const float* __restrict__ in,
                                    bf16_t* __restrict__ out) {
  const int i = blockIdx.x * blockDim.x + threadIdx.x;
  f32x4 v0 = *(const f32x4*)&in[(size_t)i * 8];
  f32x4 v1 = *(const f32x4*)&in[(size_t)i * 8 + 4];
  bf16x8 o;
  o[0] = (bf16_t)v0[0]; o[1] = (bf16_t)v0[1]; o[2] = (bf16_t)v0[2]; o[3] = (bf16_t)v0[3];
  o[4] = (bf16_t)v1[0]; o[5] = (bf16_t)v1[1]; o[6] = (bf16_t)v1[2]; o[7] = (bf16_t)v1[3];
  *(bf16x8*)&out[(size_t)i * 8] = o;
}

// ---------------- K0b: weight [512][512] f32 -> wT [512][512] bf16 (transpose) ----------------
__global__ void transpose_cvt_kernel(const float* __restrict__ in,
                                     bf16_t* __restrict__ out) {
  __shared__ float t[32][33];
  const int ti = blockIdx.x;  // din tile
  const int tj = blockIdx.y;  // dout tile
  const int c = threadIdx.x & 31;
  const int r0 = threadIdx.x >> 5;  // 0..7
  #pragma unroll
  for (int p = 0; p < 4; ++p) {
    int r = r0 + p * 8;
    t[r][c] = in[(size_t)(ti * 32 + r) * 512 + tj * 32 + c];
  }
  __syncthreads();
  #pragma unroll
  for (int p = 0; p < 4; ++p) {
    int r = r0 + p * 8;
    out[(size_t)(tj * 32 + r) * 512 + ti * 32 + c] = (bf16_t)t[c][r];
  }
}

// ---------------- GEMM-BT: C[m][n] = sum_k A[m][k] * Bt[n][k] ----------------
// A_IS_F32: A is f32 in global, converted to bf16 during reg-staging (w/ prefetch).
//           else A is bf16 and staged via global_load_lds.
// RELU_F32_OUT: epilogue relu + f32 store; else bf16 store, no relu.
// Tile 128x128, BK=64, 512 threads = 8 waves as 2(M) x 4(N); per-wave 64x32.
template<int A_IS_F32, int RELU_F32_OUT>
__global__ __launch_bounds__(512) void gemm_bt_kernel(
    const void* __restrict__ Av, const bf16_t* __restrict__ Bt,
    void* __restrict__ Cv, int K, int lda, int ldb, int ldc, int ntiles) {
  constexpr int BM = 128, BN = 128, BK = 64;
  __shared__ alignas(16) bf16_t Alds[BM][BK];
  __shared__ alignas(16) bf16_t Blds[BN][BK];

  const int tid  = threadIdx.x;
  const int lane = tid & 63;
  const int w    = tid >> 6;
  const int wr   = w >> 2;  // 0..1
  const int wc   = w & 3;   // 0..3

  // XCD-chunked swizzle (grid divisible by 8): each XCD owns a contiguous
  // range of logical tiles -> the 4 n-tiles sharing an adj row-band co-locate.
  const int nwg = gridDim.x;
  const int cpx = nwg >> 3;
  const int bid = blockIdx.x;
  const int swz = (bid & 7) * cpx + (bid >> 3);
  const int mt = swz / ntiles;
  const int nt = swz - mt * ntiles;
  const int row0 = mt * BM;
  const int col0 = nt * BN;

  f32x4 acc[4][2];
  #pragma unroll
  for (int mi = 0; mi < 4; ++mi)
    #pragma unroll
    for (int ni = 0; ni < 2; ++ni)
      acc[mi][ni] = (f32x4){0.f, 0.f, 0.f, 0.f};

  const float*  Af = (const float*)Av;
  const bf16_t* Ab = (const bf16_t*)Av;

  // B staging geometry: chunk c in {tid, tid+512}; row=c>>3, col8=c&7 (16B each)
  const int brow = tid >> 3;
  const int bc8  = tid & 7;

  // A reg-staging geometry (f32 path): 4 float4 chunks per thread
  int arow[4], ac4[4];
  f32x4 apref[4];
  if constexpr (A_IS_F32) {
    #pragma unroll
    for (int i = 0; i < 4; ++i) {
      int idx = tid + i * 512;
      arow[i] = idx >> 4;
      ac4[i]  = idx & 15;
      apref[i] = *(const f32x4*)&Af[(size_t)(row0 + arow[i]) * lda + ac4[i] * 4];
    }
  }

  const int nkt = K / BK;
  for (int kt = 0; kt < nkt; ++kt) {
    const int k0 = kt * BK;
    // stage B: async global->LDS, 16B/lane, 2 issues cover 128x64 bf16
    gload_lds16(&Bt[(size_t)(col0 + brow) * ldb + k0 + bc8 * 8], &Blds[brow][bc8 * 8]);
    gload_lds16(&Bt[(size_t)(col0 + brow + 64) * ldb + k0 + bc8 * 8], &Blds[brow + 64][bc8 * 8]);
    if constexpr (A_IS_F32) {
      #pragma unroll
      for (int i = 0; i < 4; ++i) {
        bf16x4 b;
        b[0] = (bf16_t)apref[i][0]; b[1] = (bf16_t)apref[i][1];
        b[2] = (bf16_t)apref[i][2]; b[3] = (bf16_t)apref[i][3];
        *(bf16x4*)&Alds[arow[i]][ac4[i] * 4] = b;
      }
    } else {
      gload_lds16(&Ab[(size_t)(row0 + brow) * lda + k0 + bc8 * 8], &Alds[brow][bc8 * 8]);
      gload_lds16(&Ab[(size_t)(row0 + brow + 64) * lda + k0 + bc8 * 8], &Alds[brow + 64][bc8 * 8]);
    }
    __syncthreads();
    // prefetch next A f32 chunk into regs; HBM latency hides under MFMAs
    if constexpr (A_IS_F32) {
      if (kt + 1 < nkt) {
        #pragma unroll
        for (int i = 0; i < 4; ++i)
          apref[i] = *(const f32x4*)&Af[(size_t)(row0 + arow[i]) * lda + (k0 + BK) + ac4[i] * 4];
      }
    }
    #pragma unroll
    for (int kk = 0; kk < 2; ++kk) {
      const int ko = kk * 32 + (lane >> 4) * 8;
      bf16x8 a[4], b[2];
      #pragma unroll
      for (int mi = 0; mi < 4; ++mi)
        a[mi] = *(const bf16x8*)&Alds[wr * 64 + mi * 16 + (lane & 15)][ko];
      #pragma unroll
      for (int ni = 0; ni < 2; ++ni)
        b[ni] = *(const bf16x8*)&Blds[wc * 32 + ni * 16 + (lane & 15)][ko];
      #pragma unroll
      for (int mi = 0; mi < 4; ++mi)
        #pragma unroll
        for (int ni = 0; ni < 2; ++ni)
          acc[mi][ni] = __builtin_amdgcn_mfma_f32_16x16x32_bf16(a[mi], b[ni], acc[mi][ni], 0, 0, 0);
    }
    __syncthreads();
  }

  // epilogue: C/D layout col=lane&15, row=(lane>>4)*4+reg  [m89-verified]
  const int rbase = row0 + wr * 64 + ((lane >> 4) << 2);
  const int cbase = col0 + wc * 32 + (lane & 15);
  if constexpr (RELU_F32_OUT) {
    float* C = (float*)Cv;
    #pragma unroll
    for (int mi = 0; mi < 4; ++mi)
      #pragma unroll
      for (int ni = 0; ni < 2; ++ni)
        #pragma unroll
        for (int j = 0; j < 4; ++j)
          C[(size_t)(rbase + mi * 16 + j) * ldc + cbase + ni * 16] =
              fmaxf(acc[mi][ni][j], 0.0f);
  } else {
    bf16_t* C = (bf16_t*)Cv;
    #pragma unroll
    for (int mi = 0; mi < 4; ++mi)
      #pragma unroll
      for (int ni = 0; ni < 2; ++ni)
        #pragma unroll
        for (int j = 0; j < 4; ++j)
          C[(size_t)(rbase + mi * 16 + j) * ldc + cbase + ni * 16] =
              (bf16_t)acc[mi][ni][j];
  }
}

extern "C" void kernel_launch(void* const* d_in, const int* in_sizes, int n_in,
                              void* d_out, int out_size, void* d_ws, size_t ws_size,
                              hipStream_t stream) {
  const int N = 8192, D = 512;
  const float* features = (const float*)d_in[0];  // [N][D]
  const float* adj      = (const float*)d_in[1];  // [N][N]
  const float* weight   = (const float*)d_in[2];  // [D][D]
  float* out = (float*)d_out;                     // [N][D] f32

  char* ws = (char*)d_ws;
  bf16_t* fb16 = (bf16_t*)ws;                                   // [N][D]   8.4 MB
  bf16_t* wT   = (bf16_t*)(ws + (size_t)N * D * 2);             // [D][D]   0.5 MB
  bf16_t* fwT  = (bf16_t*)(ws + (size_t)N * D * 2 + (size_t)D * D * 2);  // [D][N] 8.4 MB

  // K0a: features f32 -> bf16 (row-major, din-contiguous)
  cvt_f32_bf16_kernel<<<(N * D / 8) / 256, 256, 0, stream>>>(features, fb16);
  // K0b: wT[dout][din] = weight[din][dout], bf16
  transpose_cvt_kernel<<<dim3(16, 16), 256, 0, stream>>>(weight, wT);
  // K1: fwT[dout][node] = sum_din wT[dout][din] * fb16[node][din]
  //     M=512, N=8192, K=512 -> grid 4*64 = 256
  gemm_bt_kernel<0, 0><<<256, 512, 0, stream>>>(wT, fb16, fwT,
                                                512, 512, 512, 8192, 64);
  // K2: out[node][dout] = relu( sum_k adj[node][k] * fwT[dout][k] )
  //     M=8192, N=512, K=8192 -> grid 64*4 = 256
  gemm_bt_kernel<1, 1><<<256, 512, 0, stream>>>(adj, fwT, out,
                                                8192, 8192, 8192, 512, 4);
}

// Round 2
// 165.744 us; speedup vs baseline: 1.2491x; 1.2491x over previous
//
#include <hip/hip_runtime.h>
#include <hip/hip_bf16.h>
#include <stdint.h>

typedef __bf16 bf16_t;
typedef __bf16 bf16x4 __attribute__((ext_vector_type(4)));
typedef __bf16 bf16x8 __attribute__((ext_vector_type(8)));
typedef float  f32x4  __attribute__((ext_vector_type(4)));

#define AS_GLOBAL __attribute__((address_space(1)))
#define AS_LDS    __attribute__((address_space(3)))

__device__ __forceinline__ void gload_lds16(const void* g, void* l) {
  __builtin_amdgcn_global_load_lds((const AS_GLOBAL void*)g,
                                   (AS_LDS void*)l, 16, 0, 0);
}

// ---------------- K0a: f32 -> bf16 elementwise (8 elems/thread) ----------------
__global__ void cvt_f32_bf16_kernel(const float* __restrict__ in,
                                    bf16_t* __restrict__ out) {
  const int i = blockIdx.x * blockDim.x + threadIdx.x;
  f32x4 v0 = *(const f32x4*)&in[(size_t)i * 8];
  f32x4 v1 = *(const f32x4*)&in[(size_t)i * 8 + 4];
  bf16x8 o;
  o[0] = (bf16_t)v0[0]; o[1] = (bf16_t)v0[1]; o[2] = (bf16_t)v0[2]; o[3] = (bf16_t)v0[3];
  o[4] = (bf16_t)v1[0]; o[5] = (bf16_t)v1[1]; o[6] = (bf16_t)v1[2]; o[7] = (bf16_t)v1[3];
  *(bf16x8*)&out[(size_t)i * 8] = o;
}

// ---------------- K0b: weight [512][512] f32 -> wT [512][512] bf16 (transpose) ----------------
__global__ void transpose_cvt_kernel(const float* __restrict__ in,
                                     bf16_t* __restrict__ out) {
  __shared__ float t[32][33];
  const int ti = blockIdx.x;  // din tile
  const int tj = blockIdx.y;  // dout tile
  const int c = threadIdx.x & 31;
  const int r0 = threadIdx.x >> 5;  // 0..7
  #pragma unroll
  for (int p = 0; p < 4; ++p) {
    int r = r0 + p * 8;
    t[r][c] = in[(size_t)(ti * 32 + r) * 512 + tj * 32 + c];
  }
  __syncthreads();
  #pragma unroll
  for (int p = 0; p < 4; ++p) {
    int r = r0 + p * 8;
    out[(size_t)(tj * 32 + r) * 512 + ti * 32 + c] = (bf16_t)t[c][r];
  }
}

// ---------------- GEMM-BT: C[m][n] = sum_k A[m][k] * Bt[n][k] ----------------
// Swizzled LDS layout: 16B chunk c (=k>>3) of row r lives at slot c ^ (r&7):
//   elem(r,k) -> r*64 + (((k>>3) ^ (r&7)) << 3) + (k&7)
// B is staged via global_load_lds (linear dest = tid*16B) with the SOURCE
// chunk pre-swizzled (rule #21: same involution on source and read).
// A (f32 path) is reg-staged + converted, ds_write at the swizzled offset.
// 2-phase double-buffer: stage(t+1 -> buf^1) issued BEFORE compute(buf),
// one barrier per K-step, loads drain at the end-of-step barrier.
template<int A_IS_F32, int RELU_F32_OUT>
__global__ __launch_bounds__(512) void gemm_bt_kernel(
    const void* __restrict__ Av, const bf16_t* __restrict__ Bt,
    void* __restrict__ Cv, int K, int lda, int ldb, int ldc, int ntiles) {
  constexpr int BM = 128, BN = 128, BK = 64;
  __shared__ alignas(16) bf16_t Al[2][BM * BK];
  __shared__ alignas(16) bf16_t Bl[2][BN * BK];

  const int tid  = threadIdx.x;
  const int lane = tid & 63;
  const int w    = tid >> 6;
  const int wr   = w >> 2;  // 0..1
  const int wc   = w & 3;   // 0..3

  // XCD-chunked swizzle (grid divisible by 8): same adj row-band co-locates.
  const int nwg = gridDim.x;
  const int cpx = nwg >> 3;
  const int bid = blockIdx.x;
  const int swz = (bid & 7) * cpx + (bid >> 3);
  const int mt = swz / ntiles;
  const int nt = swz - mt * ntiles;
  const int row0 = mt * BM;
  const int col0 = nt * BN;

  f32x4 acc[4][2];
  #pragma unroll
  for (int mi = 0; mi < 4; ++mi)
    #pragma unroll
    for (int ni = 0; ni < 2; ++ni)
      acc[mi][ni] = (f32x4){0.f, 0.f, 0.f, 0.f};

  const float*  Af = (const float*)Av;
  const bf16_t* Ab = (const bf16_t*)Av;

  // staging geometry: row = tid>>3, 16B chunk = tid&7; swizzled source chunk
  const int brow = tid >> 3;
  const int bc8  = tid & 7;
  const int bc8s = bc8 ^ (brow & 7);   // (brow+64)&7 == brow&7

  // A reg-staging geometry (f32 path): 4 float4 chunks per thread
  int arow[4], ac4[4], awofs[4];
  f32x4 apref[4];
  if constexpr (A_IS_F32) {
    #pragma unroll
    for (int i = 0; i < 4; ++i) {
      int idx = tid + i * 512;
      arow[i] = idx >> 4;
      ac4[i]  = idx & 15;  // 8B chunk
      awofs[i] = arow[i] * 64 + (((ac4[i] >> 1) ^ (arow[i] & 7)) << 3) + (ac4[i] & 1) * 4;
    }
  }

  const int nkt = K / BK;

  auto stageB = [&](int b, int k0) {
    gload_lds16(&Bt[(size_t)(col0 + brow) * ldb + k0 + bc8s * 8], &Bl[b][tid * 8]);
    gload_lds16(&Bt[(size_t)(col0 + brow + 64) * ldb + k0 + bc8s * 8], &Bl[b][tid * 8 + 64 * 64]);
  };
  auto stageA16 = [&](int b, int k0) {
    gload_lds16(&Ab[(size_t)(row0 + brow) * lda + k0 + bc8s * 8], &Al[b][tid * 8]);
    gload_lds16(&Ab[(size_t)(row0 + brow + 64) * lda + k0 + bc8s * 8], &Al[b][tid * 8 + 64 * 64]);
  };
  auto loadA = [&](int k0) {
    #pragma unroll
    for (int i = 0; i < 4; ++i)
      apref[i] = *(const f32x4*)&Af[(size_t)(row0 + arow[i]) * lda + k0 + ac4[i] * 4];
  };
  auto writeA = [&](int b) {
    #pragma unroll
    for (int i = 0; i < 4; ++i) {
      bf16x4 v;
      v[0] = (bf16_t)apref[i][0]; v[1] = (bf16_t)apref[i][1];
      v[2] = (bf16_t)apref[i][2]; v[3] = (bf16_t)apref[i][3];
      *(bf16x4*)&Al[b][awofs[i]] = v;
    }
  };

  // ---- prologue: fill buffer 0, preload A regs for tile 1 ----
  stageB(0, 0);
  if constexpr (A_IS_F32) {
    loadA(0);
    writeA(0);
    if (nkt > 1) loadA(BK);
  } else {
    stageA16(0, 0);
  }
  __syncthreads();

  int cur = 0;
  for (int kt = 0; kt < nkt; ++kt) {
    // phase 1: issue next-tile staging into buf^1 (drains at end-of-step barrier)
    if (kt + 1 < nkt) {
      stageB(cur ^ 1, (kt + 1) * BK);
      if constexpr (A_IS_F32) {
        writeA(cur ^ 1);                       // apref holds tile kt+1
        if (kt + 2 < nkt) loadA((kt + 2) * BK); // issue loads for tile kt+2
      } else {
        stageA16(cur ^ 1, (kt + 1) * BK);
      }
    }
    // phase 2: compute on buf cur
    #pragma unroll
    for (int kk = 0; kk < 2; ++kk) {
      bf16x8 a[4], b[2];
      #pragma unroll
      for (int mi = 0; mi < 4; ++mi) {
        const int r = wr * 64 + mi * 16 + (lane & 15);
        const int c16 = kk * 4 + (lane >> 4);
        a[mi] = *(const bf16x8*)&Al[cur][r * 64 + ((c16 ^ (r & 7)) << 3)];
      }
      #pragma unroll
      for (int ni = 0; ni < 2; ++ni) {
        const int r = wc * 32 + ni * 16 + (lane & 15);
        const int c16 = kk * 4 + (lane >> 4);
        b[ni] = *(const bf16x8*)&Bl[cur][r * 64 + ((c16 ^ (r & 7)) << 3)];
      }
      #pragma unroll
      for (int mi = 0; mi < 4; ++mi)
        #pragma unroll
        for (int ni = 0; ni < 2; ++ni)
          acc[mi][ni] = __builtin_amdgcn_mfma_f32_16x16x32_bf16(a[mi], b[ni], acc[mi][ni], 0, 0, 0);
    }
    __syncthreads();
    cur ^= 1;
  }

  // epilogue: C/D layout col=lane&15, row=(lane>>4)*4+reg  [m89-verified]
  const int rbase = row0 + wr * 64 + ((lane >> 4) << 2);
  const int cbase = col0 + wc * 32 + (lane & 15);
  if constexpr (RELU_F32_OUT) {
    float* C = (float*)Cv;
    #pragma unroll
    for (int mi = 0; mi < 4; ++mi)
      #pragma unroll
      for (int ni = 0; ni < 2; ++ni)
        #pragma unroll
        for (int j = 0; j < 4; ++j)
          C[(size_t)(rbase + mi * 16 + j) * ldc + cbase + ni * 16] =
              fmaxf(acc[mi][ni][j], 0.0f);
  } else {
    bf16_t* C = (bf16_t*)Cv;
    #pragma unroll
    for (int mi = 0; mi < 4; ++mi)
      #pragma unroll
      for (int ni = 0; ni < 2; ++ni)
        #pragma unroll
        for (int j = 0; j < 4; ++j)
          C[(size_t)(rbase + mi * 16 + j) * ldc + cbase + ni * 16] =
              (bf16_t)acc[mi][ni][j];
  }
}

extern "C" void kernel_launch(void* const* d_in, const int* in_sizes, int n_in,
                              void* d_out, int out_size, void* d_ws, size_t ws_size,
                              hipStream_t stream) {
  const int N = 8192, D = 512;
  const float* features = (const float*)d_in[0];  // [N][D]
  const float* adj      = (const float*)d_in[1];  // [N][N]
  const float* weight   = (const float*)d_in[2];  // [D][D]
  float* out = (float*)d_out;                     // [N][D] f32

  char* ws = (char*)d_ws;
  bf16_t* fb16 = (bf16_t*)ws;                                   // [N][D]   8.4 MB
  bf16_t* wT   = (bf16_t*)(ws + (size_t)N * D * 2);             // [D][D]   0.5 MB
  bf16_t* fwT  = (bf16_t*)(ws + (size_t)N * D * 2 + (size_t)D * D * 2);  // [D][N] 8.4 MB

  // K0a: features f32 -> bf16 (row-major, din-contiguous)
  cvt_f32_bf16_kernel<<<(N * D / 8) / 256, 256, 0, stream>>>(features, fb16);
  // K0b: wT[dout][din] = weight[din][dout], bf16
  transpose_cvt_kernel<<<dim3(16, 16), 256, 0, stream>>>(weight, wT);
  // K1: fwT[dout][node] = sum_din wT[dout][din] * fb16[node][din]
  //     M=512, N=8192, K=512 -> grid 4*64 = 256
  gemm_bt_kernel<0, 0><<<256, 512, 0, stream>>>(wT, fb16, fwT,
                                                512, 512, 512, 8192, 64);
  // K2: out[node][dout] = relu( sum_k adj[node][k] * fwT[dout][k] )
  //     M=8192, N=512, K=8192 -> grid 64*4 = 256
  gemm_bt_kernel<1, 1><<<256, 512, 0, stream>>>(adj, fwT, out,
                                                8192, 8192, 8192, 512, 4);
}